// Round 14
// baseline (238.800 us; speedup 1.0000x reference)
//
#include <hip/hip_runtime.h>
#include <hip/hip_cooperative_groups.h>

#define NN 1024
#define BB 64
#define CHUNKS 32
#define KS 8   // k-splits per batch in the DFT phase

// ---------------------------------------------------------------------------
// Kernel 1: balanced diagonal partial sums (R9-exact, best known).
__global__ __launch_bounds__(256) void diag_partial(const float* __restrict__ attns,
                                                    float* __restrict__ partial) {
    __shared__ float lds[4][1032];
    const int t = blockIdx.x;       // 0..31
    const int b = blockIdx.y;
    const int tid = threadIdx.x;
    const int w = tid >> 6, lane = tid & 63;

    float4 acc0 = make_float4(0.f, 0.f, 0.f, 0.f);
    float4 acc1 = acc0, acc2 = acc0, acc3 = acc0;

    const float* base = attns + (size_t)b * NN * NN;

#define ROWPAIR(k, fT, fB, nvT, nvB)                                          \
    const int jbT##k = 16 * t + 4 * (k);                                      \
    const int nvT = 256 - 4 * t - (k);                                        \
    const float4* fT = (const float4*)(base + (size_t)(jbT##k + w) * NN + jbT##k); \
    const int jbB##k = 1008 - 16 * t + 4 * (k);                               \
    const int nvB = 4 + 4 * t - (k);                                          \
    const float4* fB = (const float4*)(base + (size_t)(jbB##k + w) * NN + jbB##k);

    ROWPAIR(0, fT0, fB0, nvT0, nvB0)
    ROWPAIR(1, fT1, fB1, nvT1, nvB1)
    ROWPAIR(2, fT2, fB2, nvT2, nvB2)
    ROWPAIR(3, fT3, fB3, nvT3, nvB3)
#undef ROWPAIR

#define LOADP(g, fT, fB, nvT, nvB)                                            \
    float4 xa##g = fT[lane];                                                  \
    float4 xb##g = fT[lane + 64];                                             \
    float4 xc##g = fT[lane + 128 < nvT - 1 ? lane + 128 : nvT - 1];           \
    float4 xd##g = fT[lane + 192 < nvT - 1 ? lane + 192 : nvT - 1];           \
    float4 ya##g = fB[lane < nvB - 1 ? lane : nvB - 1];                       \
    float4 yb##g = fB[lane + 64 < nvB - 1 ? lane + 64 : nvB - 1];

#define CONSP(g, nvT, nvB)                                                    \
    {                                                                         \
        const bool ok2 = lane + 128 < nvT, ok3 = lane + 192 < nvT;            \
        const bool p0 = lane < nvB, p1 = lane + 64 < nvB;                     \
        xc##g.x = ok2 ? xc##g.x : 0.f; xc##g.y = ok2 ? xc##g.y : 0.f;         \
        xc##g.z = ok2 ? xc##g.z : 0.f; xc##g.w = ok2 ? xc##g.w : 0.f;         \
        xd##g.x = ok3 ? xd##g.x : 0.f; xd##g.y = ok3 ? xd##g.y : 0.f;         \
        xd##g.z = ok3 ? xd##g.z : 0.f; xd##g.w = ok3 ? xd##g.w : 0.f;         \
        ya##g.x = p0 ? ya##g.x : 0.f; ya##g.y = p0 ? ya##g.y : 0.f;           \
        ya##g.z = p0 ? ya##g.z : 0.f; ya##g.w = p0 ? ya##g.w : 0.f;           \
        yb##g.x = p1 ? yb##g.x : 0.f; yb##g.y = p1 ? yb##g.y : 0.f;           \
        yb##g.z = p1 ? yb##g.z : 0.f; yb##g.w = p1 ? yb##g.w : 0.f;           \
        if (lane == 0) {                                                      \
            if (w > 0) { xa##g.x = 0.f; ya##g.x = 0.f; }                      \
            if (w > 1) { xa##g.y = 0.f; ya##g.y = 0.f; }                      \
            if (w > 2) { xa##g.z = 0.f; ya##g.z = 0.f; }                      \
        }                                                                     \
        acc0.x += xa##g.x + ya##g.x; acc0.y += xa##g.y + ya##g.y;             \
        acc0.z += xa##g.z + ya##g.z; acc0.w += xa##g.w + ya##g.w;             \
        acc1.x += xb##g.x + yb##g.x; acc1.y += xb##g.y + yb##g.y;             \
        acc1.z += xb##g.z + yb##g.z; acc1.w += xb##g.w + yb##g.w;             \
        acc2.x += xc##g.x; acc2.y += xc##g.y;                                 \
        acc2.z += xc##g.z; acc2.w += xc##g.w;                                 \
        acc3.x += xd##g.x; acc3.y += xd##g.y;                                 \
        acc3.z += xd##g.z; acc3.w += xd##g.w;                                 \
    }

    LOADP(0, fT0, fB0, nvT0, nvB0)
    LOADP(1, fT1, fB1, nvT1, nvB1)
    LOADP(2, fT2, fB2, nvT2, nvB2)
    CONSP(0, nvT0, nvB0)
    LOADP(3, fT3, fB3, nvT3, nvB3)
    CONSP(1, nvT1, nvB1)
    CONSP(2, nvT2, nvB2)
    CONSP(3, nvT3, nvB3)
#undef LOADP
#undef CONSP

    float4* lrow = (float4*)lds[w];
    lrow[lane]       = acc0;
    lrow[lane + 64]  = acc1;
    lrow[lane + 128] = acc2;
    lrow[lane + 192] = acc3;
    if (tid < 32) lds[tid >> 3][1024 + (tid & 7)] = 0.f;
    __syncthreads();

    float* outp = partial + ((size_t)b * CHUNKS + t) * NN;
    {
        const int d0 = tid * 4;
        float4 o;
        o.x = (lds[0][d0]     + lds[1][d0 + 1]) + (lds[2][d0 + 2] + lds[3][d0 + 3]);
        o.y = (lds[0][d0 + 1] + lds[1][d0 + 2]) + (lds[2][d0 + 3] + lds[3][d0 + 4]);
        o.z = (lds[0][d0 + 2] + lds[1][d0 + 3]) + (lds[2][d0 + 4] + lds[3][d0 + 5]);
        o.w = (lds[0][d0 + 3] + lds[1][d0 + 4]) + (lds[2][d0 + 5] + lds[3][d0 + 6]);
        ((float4*)outp)[tid] = o;
    }
}

// ---------------------------------------------------------------------------
// Kernel 2 (cooperative): reduce -> grid.sync -> DFT -> grid.sync -> finalize.
// 512 blocks x 512 threads. Block roles: reduce (b = blk>>3, dq = blk&7);
// dft (b = blk>>3, ks = blk&7); finalize: block 0.
__global__ __launch_bounds__(512) void fused_tail(const float* __restrict__ partial,
                                                  float* __restrict__ wpm,
                                                  float* __restrict__ kparts,
                                                  float* __restrict__ out) {
    __shared__ float wp[512], wm[512];
    __shared__ float2 tw[NN];
    __shared__ float redmax[8], redsum[8];
    const int blk = blockIdx.x;
    const int b = blk >> 3;
    const int tid = threadIdx.x;
    const float C = 6.283185307179586f / 1024.0f;
    cooperative_groups::grid_group grid = cooperative_groups::this_grid();

    // ---- phase 1: reduce chunk partials -> parity-split means ----
    {
        const int dq = blk & 7;
        const int d = dq * 64 + (tid & 63);
        const int cq = tid >> 6;            // 0..7, 4 chunks each
        const float* pb = partial + (size_t)b * CHUNKS * NN;
        float slo = 0.f, shi = 0.f;
#pragma unroll
        for (int j = 0; j < 4; ++j) {
            const int c = cq * 4 + j;
            slo += pb[c * NN + d];
            shi += pb[c * NN + d + 512];
        }
        // reuse wp/wm + tw as scratch: [512] slo, [512] shi via tw region
        float* slo_s = (float*)tw;           // 512 floats
        float* shi_s = ((float*)tw) + 512;   // 512 floats
        slo_s[tid] = slo; shi_s[tid] = shi;
        __syncthreads();
        if (tid < 64) {
            float l = 0.f, h = 0.f;
#pragma unroll
            for (int q = 0; q < 8; ++q) {
                l += slo_s[tid + 64 * q];
                h += shi_s[tid + 64 * q];
            }
            const float wlo = l / (float)(NN - d);
            const float whi = h / (float)(512 - d);
            wpm[(size_t)b * NN + d]       = wlo + whi;   // wp
            wpm[(size_t)b * NN + 512 + d] = wlo - whi;   // wm
        }
    }
    __threadfence();
    grid.sync();

    // ---- phase 2: even/odd-decimated DFT (R9-exact core) ----
    {
        const int ks = blk & 7;
        const float* src = wpm + (size_t)b * NN;
        wp[tid & 511] = src[tid & 511];
        wm[tid & 511] = src[512 + (tid & 511)];
        float s0, c0, s1, c1;
        __sincosf((float)tid * C, &s0, &c0);
        __sincosf((float)(tid + 512) * C, &s1, &c1);
        tw[tid]       = make_float2(c0, -s0);
        tw[tid + 512] = make_float2(c1, -s1);
        __syncthreads();

        const int k = 1 + ks * 64 + (tid >> 3);
        const int dp = tid & 7;
        const float* wsel = (k & 1) ? wm : wp;
        const int kstep = (k << 3) & (NN - 1);

        float re = 0.f, im = 0.f;
        int t = (k * dp) & (NN - 1);
#pragma unroll 8
        for (int it = 0; it < 64; ++it) {
            const float2 c = tw[t];
            const float wv = wsel[dp + 8 * it];
            re = fmaf(wv, c.x, re);
            im = fmaf(wv, c.y, im);
            t = (t + kstep) & (NN - 1);
        }
        re += __shfl_xor(re, 1, 64); re += __shfl_xor(re, 2, 64); re += __shfl_xor(re, 4, 64);
        im += __shfl_xor(im, 1, 64); im += __shfl_xor(im, 2, 64); im += __shfl_xor(im, 4, 64);
        const float spec = sqrtf(re * re + im * im);

        float mx = spec;
        float sm = (dp == 0) ? spec : 0.f;
        for (int off = 8; off < 64; off <<= 1) {
            mx = fmaxf(mx, __shfl_xor(mx, off, 64));
            sm += __shfl_xor(sm, off, 64);
        }
        const int wid = tid >> 6, lane = tid & 63;
        if (lane == 0) { redmax[wid] = mx; redsum[wid] = sm; }
        __syncthreads();
        if (tid == 0) {
            float M = redmax[0], S = redsum[0];
            for (int i = 1; i < 8; ++i) { M = fmaxf(M, redmax[i]); S += redsum[i]; }
            kparts[((size_t)b * KS + ks) * 2 + 0] = M;
            kparts[((size_t)b * KS + ks) * 2 + 1] = S;
        }
    }
    __threadfence();
    grid.sync();

    // ---- phase 3: finalize (block 0, one wave) ----
    if (blk == 0 && tid < 64) {
        float M = 0.f, S = 0.f;
#pragma unroll
        for (int s = 0; s < KS; ++s) {
            M = fmaxf(M, kparts[((size_t)tid * KS + s) * 2 + 0]);
            S += kparts[((size_t)tid * KS + s) * 2 + 1];
        }
        float j = 1.0f - M / S;
        for (int off = 32; off; off >>= 1) j += __shfl_xor(j, off, 64);
        if (tid == 0) out[0] = j * (1.0f / 64.0f);
    }
}

// ---------------------------------------------------------------------------
extern "C" void kernel_launch(void* const* d_in, const int* in_sizes, int n_in,
                              void* d_out, int out_size, void* d_ws, size_t ws_size,
                              hipStream_t stream) {
    const float* attns = (const float*)d_in[0];
    float* out = (float*)d_out;

    // workspace: [partial: B*CHUNKS*N = 8MB] [wpm: B*N] [kparts: B*KS*2]
    float* partial = (float*)d_ws;
    float* wpm     = partial + (size_t)BB * CHUNKS * NN;
    float* kparts  = wpm + (size_t)BB * NN;

    diag_partial<<<dim3(CHUNKS, BB), 256, 0, stream>>>(attns, partial);

    void* args[] = {(void*)&partial, (void*)&wpm, (void*)&kparts, (void*)&out};
    hipLaunchCooperativeKernel((const void*)fused_tail, dim3(512), dim3(512),
                               args, 0, stream);
}

// Round 15
// 39.347 us; speedup vs baseline: 6.0691x; 6.0691x over previous
//
#include <hip/hip_runtime.h>

#define NN 1024
#define BB 64
#define CHUNKS 32
#define KS 8   // k-splits per batch in the DFT kernel

#if __has_builtin(__builtin_amdgcn_make_buffer_rsrc) && __has_builtin(__builtin_amdgcn_raw_buffer_load_b128)
#define USE_SRD 1
#else
#define USE_SRD 0
#endif

#if USE_SRD
typedef unsigned int u32x4 __attribute__((ext_vector_type(4)));
static __device__ __forceinline__ float4 srd_load(__amdgpu_buffer_rsrc_t r, int off) {
    u32x4 v = __builtin_amdgcn_raw_buffer_load_b128(r, off, 0, 0);
    float4 f;
    f.x = __uint_as_float(v.x);
    f.y = __uint_as_float(v.y);
    f.z = __uint_as_float(v.z);
    f.w = __uint_as_float(v.w);
    return f;
}
#endif

// ---------------------------------------------------------------------------
// Kernel 1: balanced diagonal partial sums, v8 (SRD bounds-checked loads).
// Block t pairs 16 LONG rows [16t,16t+16) with 16 SHORT rows
// [1008-16t,1008-16t+16). Wave w takes rows ≡ w (mod 4): r = w constant.
// Fixed (lane,group,comp)->d register map: d = 4*(lane+64*g) + comp - w.
// SRD num_records = row bytes -> OOB lanes return 0 in hardware: no clamps,
// no cndmask zeroing, no duplicate tail loads. Head (j<i at lane 0) fixed
// with 3 scalar-guarded zeroings. Pipeline: L0 L1 L2 C0 L3 C1 C2 C3.
__global__ __launch_bounds__(256) void diag_partial(const float* __restrict__ attns,
                                                    float* __restrict__ partial) {
    __shared__ float lds[4][1032];
    const int t = blockIdx.x;       // 0..31
    const int b = blockIdx.y;
    const int tid = threadIdx.x;
    const int w = tid >> 6, lane = tid & 63;

    float4 acc0 = make_float4(0.f, 0.f, 0.f, 0.f);
    float4 acc1 = acc0, acc2 = acc0, acc3 = acc0;

    const float* base = attns + (size_t)b * NN * NN;

#if USE_SRD
    const int voff = lane * 16;

#define ROWPAIR(g, srdT, srdB)                                                \
    const int jbT##g = 16 * t + 4 * (g);                                      \
    const int nvT##g = 256 - 4 * t - (g);                                     \
    __amdgpu_buffer_rsrc_t srdT = __builtin_amdgcn_make_buffer_rsrc(          \
        (void*)(base + (size_t)(jbT##g + w) * NN + jbT##g), (short)0,         \
        nvT##g * 16, 0x00020000);                                             \
    const int jbB##g = 1008 - 16 * t + 4 * (g);                               \
    const int nvB##g = 4 + 4 * t - (g);                                       \
    __amdgpu_buffer_rsrc_t srdB = __builtin_amdgcn_make_buffer_rsrc(          \
        (void*)(base + (size_t)(jbB##g + w) * NN + jbB##g), (short)0,         \
        nvB##g * 16, 0x00020000);

    ROWPAIR(0, srdT0, srdB0)
    ROWPAIR(1, srdT1, srdB1)
    ROWPAIR(2, srdT2, srdB2)
    ROWPAIR(3, srdT3, srdB3)
#undef ROWPAIR

#define LOADP(g, srdT, srdB)                                                  \
    float4 xa##g = srd_load(srdT, voff);                                      \
    float4 xb##g = srd_load(srdT, voff + 1024);                               \
    float4 xc##g = srd_load(srdT, voff + 2048);                               \
    float4 xd##g = srd_load(srdT, voff + 3072);                               \
    float4 ya##g = srd_load(srdB, voff);                                      \
    float4 yb##g = srd_load(srdB, voff + 1024);

#define CONSP(g)                                                              \
    {                                                                         \
        if (lane == 0) {                                                      \
            if (w > 0) { xa##g.x = 0.f; ya##g.x = 0.f; }                      \
            if (w > 1) { xa##g.y = 0.f; ya##g.y = 0.f; }                      \
            if (w > 2) { xa##g.z = 0.f; ya##g.z = 0.f; }                      \
        }                                                                     \
        acc0.x += xa##g.x + ya##g.x; acc0.y += xa##g.y + ya##g.y;             \
        acc0.z += xa##g.z + ya##g.z; acc0.w += xa##g.w + ya##g.w;             \
        acc1.x += xb##g.x + yb##g.x; acc1.y += xb##g.y + yb##g.y;             \
        acc1.z += xb##g.z + yb##g.z; acc1.w += xb##g.w + yb##g.w;             \
        acc2.x += xc##g.x; acc2.y += xc##g.y;                                 \
        acc2.z += xc##g.z; acc2.w += xc##g.w;                                 \
        acc3.x += xd##g.x; acc3.y += xd##g.y;                                 \
        acc3.z += xd##g.z; acc3.w += xd##g.w;                                 \
    }

    LOADP(0, srdT0, srdB0)
    LOADP(1, srdT1, srdB1)
    LOADP(2, srdT2, srdB2)
    CONSP(0)
    LOADP(3, srdT3, srdB3)
    CONSP(1)
    CONSP(2)
    CONSP(3)
#undef LOADP
#undef CONSP

#else  // fallback: exact R9 clamp+mask path

#define ROWPAIR(k, fT, fB, nvT, nvB)                                          \
    const int jbT##k = 16 * t + 4 * (k);                                      \
    const int nvT = 256 - 4 * t - (k);                                        \
    const float4* fT = (const float4*)(base + (size_t)(jbT##k + w) * NN + jbT##k); \
    const int jbB##k = 1008 - 16 * t + 4 * (k);                               \
    const int nvB = 4 + 4 * t - (k);                                          \
    const float4* fB = (const float4*)(base + (size_t)(jbB##k + w) * NN + jbB##k);

    ROWPAIR(0, fT0, fB0, nvT0, nvB0)
    ROWPAIR(1, fT1, fB1, nvT1, nvB1)
    ROWPAIR(2, fT2, fB2, nvT2, nvB2)
    ROWPAIR(3, fT3, fB3, nvT3, nvB3)
#undef ROWPAIR

#define LOADP(g, fT, fB, nvT, nvB)                                            \
    float4 xa##g = fT[lane];                                                  \
    float4 xb##g = fT[lane + 64];                                             \
    float4 xc##g = fT[lane + 128 < nvT - 1 ? lane + 128 : nvT - 1];           \
    float4 xd##g = fT[lane + 192 < nvT - 1 ? lane + 192 : nvT - 1];           \
    float4 ya##g = fB[lane < nvB - 1 ? lane : nvB - 1];                       \
    float4 yb##g = fB[lane + 64 < nvB - 1 ? lane + 64 : nvB - 1];

#define CONSP(g, nvT, nvB)                                                    \
    {                                                                         \
        const bool ok2 = lane + 128 < nvT, ok3 = lane + 192 < nvT;            \
        const bool p0 = lane < nvB, p1 = lane + 64 < nvB;                     \
        xc##g.x = ok2 ? xc##g.x : 0.f; xc##g.y = ok2 ? xc##g.y : 0.f;         \
        xc##g.z = ok2 ? xc##g.z : 0.f; xc##g.w = ok2 ? xc##g.w : 0.f;         \
        xd##g.x = ok3 ? xd##g.x : 0.f; xd##g.y = ok3 ? xd##g.y : 0.f;         \
        xd##g.z = ok3 ? xd##g.z : 0.f; xd##g.w = ok3 ? xd##g.w : 0.f;         \
        ya##g.x = p0 ? ya##g.x : 0.f; ya##g.y = p0 ? ya##g.y : 0.f;           \
        ya##g.z = p0 ? ya##g.z : 0.f; ya##g.w = p0 ? ya##g.w : 0.f;           \
        yb##g.x = p1 ? yb##g.x : 0.f; yb##g.y = p1 ? yb##g.y : 0.f;           \
        yb##g.z = p1 ? yb##g.z : 0.f; yb##g.w = p1 ? yb##g.w : 0.f;           \
        if (lane == 0) {                                                      \
            if (w > 0) { xa##g.x = 0.f; ya##g.x = 0.f; }                      \
            if (w > 1) { xa##g.y = 0.f; ya##g.y = 0.f; }                      \
            if (w > 2) { xa##g.z = 0.f; ya##g.z = 0.f; }                      \
        }                                                                     \
        acc0.x += xa##g.x + ya##g.x; acc0.y += xa##g.y + ya##g.y;             \
        acc0.z += xa##g.z + ya##g.z; acc0.w += xa##g.w + ya##g.w;             \
        acc1.x += xb##g.x + yb##g.x; acc1.y += xb##g.y + yb##g.y;             \
        acc1.z += xb##g.z + yb##g.z; acc1.w += xb##g.w + yb##g.w;             \
        acc2.x += xc##g.x; acc2.y += xc##g.y;                                 \
        acc2.z += xc##g.z; acc2.w += xc##g.w;                                 \
        acc3.x += xd##g.x; acc3.y += xd##g.y;                                 \
        acc3.z += xd##g.z; acc3.w += xd##g.w;                                 \
    }

    LOADP(0, fT0, fB0, nvT0, nvB0)
    LOADP(1, fT1, fB1, nvT1, nvB1)
    LOADP(2, fT2, fB2, nvT2, nvB2)
    CONSP(0, nvT0, nvB0)
    LOADP(3, fT3, fB3, nvT3, nvB3)
    CONSP(1, nvT1, nvB1)
    CONSP(2, nvT2, nvB2)
    CONSP(3, nvT3, nvB3)
#undef LOADP
#undef CONSP
#endif

    // dump: lds[w][4*(lane+64*g)+comp] — bijective onto [0,1024) per wave
    float4* lrow = (float4*)lds[w];
    lrow[lane]       = acc0;
    lrow[lane + 64]  = acc1;
    lrow[lane + 128] = acc2;
    lrow[lane + 192] = acc3;
    if (tid < 32) lds[tid >> 3][1024 + (tid & 7)] = 0.f;
    __syncthreads();

    // partial[b][t][d] = sum over waves of lds[wv][d + wv]; float4 store
    float* outp = partial + ((size_t)b * CHUNKS + t) * NN;
    {
        const int d0 = tid * 4;
        float4 o;
        o.x = (lds[0][d0]     + lds[1][d0 + 1]) + (lds[2][d0 + 2] + lds[3][d0 + 3]);
        o.y = (lds[0][d0 + 1] + lds[1][d0 + 2]) + (lds[2][d0 + 3] + lds[3][d0 + 4]);
        o.z = (lds[0][d0 + 2] + lds[1][d0 + 3]) + (lds[2][d0 + 4] + lds[3][d0 + 5]);
        o.w = (lds[0][d0 + 3] + lds[1][d0 + 4]) + (lds[2][d0 + 5] + lds[3][d0 + 6]);
        ((float4*)outp)[tid] = o;
    }
}

// ---------------------------------------------------------------------------
// Kernel 2: reduce chunk partials -> parity-split means, v2 (R9-exact).
__global__ __launch_bounds__(256) void reduce_waves(const float* __restrict__ partial,
                                                    float* __restrict__ wpm) {
    __shared__ float slo_s[256], shi_s[256];
    const int blk = blockIdx.x;
    const int b = blk >> 3;
    const int dq = blk & 7;
    const int tid = threadIdx.x;
    const int d = dq * 64 + (tid & 63);
    const int cq = tid >> 6;            // 0..3
    const float* pb = partial + (size_t)b * CHUNKS * NN;
    float slo = 0.f, shi = 0.f;
#pragma unroll
    for (int j = 0; j < 8; ++j) {
        const int c = cq * 8 + j;
        slo += pb[c * NN + d];
        shi += pb[c * NN + d + 512];
    }
    slo_s[tid] = slo; shi_s[tid] = shi;
    __syncthreads();
    if (tid < 64) {
        const float l = (slo_s[tid] + slo_s[tid + 64]) + (slo_s[tid + 128] + slo_s[tid + 192]);
        const float h = (shi_s[tid] + shi_s[tid + 64]) + (shi_s[tid + 128] + shi_s[tid + 192]);
        const float wlo = l / (float)(NN - d);
        const float whi = h / (float)(512 - d);
        wpm[(size_t)b * NN + d]       = wlo + whi;   // wp
        wpm[(size_t)b * NN + 512 + d] = wlo - whi;   // wm
    }
}

// ---------------------------------------------------------------------------
// Kernel 3: even/odd-decimated DFT, float2 twiddles (R9-exact).
__global__ __launch_bounds__(512) void dft_part(const float* __restrict__ wpm,
                                                float* __restrict__ kparts) {
    __shared__ float wp[512], wm[512];
    __shared__ float2 tw[NN];       // (cos, -sin)
    __shared__ float redmax[8], redsum[8];
    const int ks = blockIdx.x & (KS - 1);
    const int b = blockIdx.x >> 3;
    const int tid = threadIdx.x;
    const float C = 6.283185307179586f / 1024.0f;

    {
        const float* src = wpm + (size_t)b * NN;
        wp[tid & 511] = src[tid & 511];
        wm[tid & 511] = src[512 + (tid & 511)];
        float s0, c0, s1, c1;
        __sincosf((float)tid * C, &s0, &c0);
        __sincosf((float)(tid + 512) * C, &s1, &c1);
        tw[tid]       = make_float2(c0, -s0);
        tw[tid + 512] = make_float2(c1, -s1);
    }
    __syncthreads();

    const int k = 1 + ks * 64 + (tid >> 3);
    const int dp = tid & 7;
    const float* wsel = (k & 1) ? wm : wp;
    const int kstep = (k << 3) & (NN - 1);

    float re = 0.f, im = 0.f;
    int t = (k * dp) & (NN - 1);
#pragma unroll 8
    for (int it = 0; it < 64; ++it) {
        const float2 c = tw[t];
        const float wv = wsel[dp + 8 * it];
        re = fmaf(wv, c.x, re);
        im = fmaf(wv, c.y, im);
        t = (t + kstep) & (NN - 1);
    }
    re += __shfl_xor(re, 1, 64); re += __shfl_xor(re, 2, 64); re += __shfl_xor(re, 4, 64);
    im += __shfl_xor(im, 1, 64); im += __shfl_xor(im, 2, 64); im += __shfl_xor(im, 4, 64);
    const float spec = sqrtf(re * re + im * im);

    float mx = spec;
    float sm = (dp == 0) ? spec : 0.f;
    for (int off = 8; off < 64; off <<= 1) {
        mx = fmaxf(mx, __shfl_xor(mx, off, 64));
        sm += __shfl_xor(sm, off, 64);
    }
    const int wid = tid >> 6, lane = tid & 63;
    if (lane == 0) { redmax[wid] = mx; redsum[wid] = sm; }
    __syncthreads();
    if (tid == 0) {
        float M = redmax[0], S = redsum[0];
        for (int i = 1; i < 8; ++i) { M = fmaxf(M, redmax[i]); S += redsum[i]; }
        kparts[((size_t)b * KS + ks) * 2 + 0] = M;
        kparts[((size_t)b * KS + ks) * 2 + 1] = S;
    }
}

// ---------------------------------------------------------------------------
// Kernel 4: judgement per batch, mean over batches (R9-exact).
__global__ __launch_bounds__(64) void finalize(const float* __restrict__ kparts,
                                               float* __restrict__ out) {
    const int lane = threadIdx.x;
    float M = 0.f, S = 0.f;
#pragma unroll
    for (int s = 0; s < KS; ++s) {
        M = fmaxf(M, kparts[((size_t)lane * KS + s) * 2 + 0]);
        S += kparts[((size_t)lane * KS + s) * 2 + 1];
    }
    float j = 1.0f - M / S;
    for (int off = 32; off; off >>= 1) j += __shfl_xor(j, off, 64);
    if (lane == 0) out[0] = j * (1.0f / 64.0f);
}

// ---------------------------------------------------------------------------
extern "C" void kernel_launch(void* const* d_in, const int* in_sizes, int n_in,
                              void* d_out, int out_size, void* d_ws, size_t ws_size,
                              hipStream_t stream) {
    const float* attns = (const float*)d_in[0];
    float* out = (float*)d_out;

    float* partial = (float*)d_ws;
    float* wpm     = partial + (size_t)BB * CHUNKS * NN;
    float* kparts  = wpm + (size_t)BB * NN;

    diag_partial<<<dim3(CHUNKS, BB), 256, 0, stream>>>(attns, partial);
    reduce_waves<<<BB * 8, 256, 0, stream>>>(partial, wpm);
    dft_part<<<BB * KS, 512, 0, stream>>>(wpm, kparts);
    finalize<<<1, 64, 0, stream>>>(kparts, out);
}

// Round 16
// 38.622 us; speedup vs baseline: 6.1829x; 1.0188x over previous
//
#include <hip/hip_runtime.h>

#define NN 1024
#define BB 64
#define CHUNKS 8
#define KS 8   // k-splits per batch in the DFT kernel

#if __has_builtin(__builtin_amdgcn_make_buffer_rsrc) && __has_builtin(__builtin_amdgcn_raw_buffer_load_b128)
#define USE_SRD 1
#else
#define USE_SRD 0
#endif

#if USE_SRD
typedef unsigned int u32x4 __attribute__((ext_vector_type(4)));
static __device__ __forceinline__ float4 srd_load(__amdgpu_buffer_rsrc_t r, int off) {
    u32x4 v = __builtin_amdgcn_raw_buffer_load_b128(r, off, 0, 0);
    float4 f;
    f.x = __uint_as_float(v.x);
    f.y = __uint_as_float(v.y);
    f.z = __uint_as_float(v.z);
    f.w = __uint_as_float(v.w);
    return f;
}
#endif

// ---------------------------------------------------------------------------
// Kernel 1: balanced diagonal partial sums, v9 (CHUNKS=8, 512 thr, SRD).
// Block t (0..7) pairs 64 LONG rows [64t,64t+64) with 64 SHORT rows
// [960-64t, 960-64t+64). Wave w (0..7) takes rows ≡ w (mod 8):
//   pair p (0..7): top  i = 64t + w + 8p   (nvT = 256-16t-2p-(w>>2) ∈ [129,256])
//                  bot  i = 960-64t + w + 8p (nvB = 16+16t-2p-(w>>2) ∈ [1,128])
// r = w&3 constant per wave; jbase = i - r; fixed register map
// d = 4*(lane+64g) + comp - r. SRD num_records = row bytes -> HW OOB zeros.
// Two passes of the proven depth-3 pipeline: L0 L1 L2 C0 L3 C1 C2 C3.
__global__ __launch_bounds__(512) void diag_partial(const float* __restrict__ attns,
                                                    float* __restrict__ partial) {
    __shared__ float lds[8][1032];
    const int t = blockIdx.x;       // 0..7
    const int b = blockIdx.y;
    const int tid = threadIdx.x;
    const int w = tid >> 6, lane = tid & 63;
    const int r = w & 3;
    const int whi = w >> 2;

    float4 acc0 = make_float4(0.f, 0.f, 0.f, 0.f);
    float4 acc1 = acc0, acc2 = acc0, acc3 = acc0;

    const float* base = attns + (size_t)b * NN * NN;

#if USE_SRD
    const int voff = lane * 16;

// pair p: jbT = 64t + 8p + 4*whi ; row i = jbT + r ; similarly bottom
#define ROWPAIR(g, p)                                                         \
    const int jbT##g = 64 * t + 8 * (p) + 4 * whi;                            \
    const int nvT##g = 256 - ((jbT##g) >> 2);                                 \
    __amdgpu_buffer_rsrc_t srdT##g = __builtin_amdgcn_make_buffer_rsrc(       \
        (void*)(base + (size_t)(jbT##g + r) * NN + jbT##g), (short)0,         \
        nvT##g * 16, 0x00020000);                                             \
    const int jbB##g = 960 - 64 * t + 8 * (p) + 4 * whi;                      \
    const int nvB##g = 256 - ((jbB##g) >> 2);                                 \
    __amdgpu_buffer_rsrc_t srdB##g = __builtin_amdgcn_make_buffer_rsrc(       \
        (void*)(base + (size_t)(jbB##g + r) * NN + jbB##g), (short)0,         \
        nvB##g * 16, 0x00020000);

#define LOADP(g)                                                              \
    float4 xa##g = srd_load(srdT##g, voff);                                   \
    float4 xb##g = srd_load(srdT##g, voff + 1024);                            \
    float4 xc##g = srd_load(srdT##g, voff + 2048);                            \
    float4 xd##g = srd_load(srdT##g, voff + 3072);                            \
    float4 ya##g = srd_load(srdB##g, voff);                                   \
    float4 yb##g = srd_load(srdB##g, voff + 1024);

#define CONSP(g)                                                              \
    {                                                                         \
        if (lane == 0) {                                                      \
            if (r > 0) { xa##g.x = 0.f; ya##g.x = 0.f; }                      \
            if (r > 1) { xa##g.y = 0.f; ya##g.y = 0.f; }                      \
            if (r > 2) { xa##g.z = 0.f; ya##g.z = 0.f; }                      \
        }                                                                     \
        acc0.x += xa##g.x + ya##g.x; acc0.y += xa##g.y + ya##g.y;             \
        acc0.z += xa##g.z + ya##g.z; acc0.w += xa##g.w + ya##g.w;             \
        acc1.x += xb##g.x + yb##g.x; acc1.y += xb##g.y + yb##g.y;             \
        acc1.z += xb##g.z + yb##g.z; acc1.w += xb##g.w + yb##g.w;             \
        acc2.x += xc##g.x; acc2.y += xc##g.y;                                 \
        acc2.z += xc##g.z; acc2.w += xc##g.w;                                 \
        acc3.x += xd##g.x; acc3.y += xd##g.y;                                 \
        acc3.z += xd##g.z; acc3.w += xd##g.w;                                 \
    }

#define QUADBODY(P0)                                                          \
    {                                                                         \
        ROWPAIR(0, (P0) + 0)                                                  \
        ROWPAIR(1, (P0) + 1)                                                  \
        ROWPAIR(2, (P0) + 2)                                                  \
        ROWPAIR(3, (P0) + 3)                                                  \
        LOADP(0)                                                              \
        LOADP(1)                                                              \
        LOADP(2)                                                              \
        CONSP(0)                                                              \
        LOADP(3)                                                              \
        CONSP(1)                                                              \
        CONSP(2)                                                              \
        CONSP(3)                                                              \
    }

    QUADBODY(0)
    QUADBODY(4)
#undef ROWPAIR
#undef LOADP
#undef CONSP
#undef QUADBODY

#else  // fallback: clamp+mask path (R9 mechanics, 8-wave geometry)

#define ROWPAIR(g, p)                                                         \
    const int jbT##g = 64 * t + 8 * (p) + 4 * whi;                            \
    const int nvT##g = 256 - ((jbT##g) >> 2);                                 \
    const float4* fT##g = (const float4*)(base + (size_t)(jbT##g + r) * NN + jbT##g); \
    const int jbB##g = 960 - 64 * t + 8 * (p) + 4 * whi;                      \
    const int nvB##g = 256 - ((jbB##g) >> 2);                                 \
    const float4* fB##g = (const float4*)(base + (size_t)(jbB##g + r) * NN + jbB##g);

#define LOADP(g)                                                              \
    float4 xa##g = fT##g[lane];                                               \
    float4 xb##g = fT##g[lane + 64];                                          \
    float4 xc##g = fT##g[lane + 128 < nvT##g - 1 ? lane + 128 : nvT##g - 1];  \
    float4 xd##g = fT##g[lane + 192 < nvT##g - 1 ? lane + 192 : nvT##g - 1];  \
    float4 ya##g = fB##g[lane < nvB##g - 1 ? lane : nvB##g - 1];              \
    float4 yb##g = fB##g[lane + 64 < nvB##g - 1 ? lane + 64 : nvB##g - 1];

#define CONSP(g)                                                              \
    {                                                                         \
        const bool ok2 = lane + 128 < nvT##g, ok3 = lane + 192 < nvT##g;      \
        const bool p0 = lane < nvB##g, p1 = lane + 64 < nvB##g;               \
        xc##g.x = ok2 ? xc##g.x : 0.f; xc##g.y = ok2 ? xc##g.y : 0.f;         \
        xc##g.z = ok2 ? xc##g.z : 0.f; xc##g.w = ok2 ? xc##g.w : 0.f;         \
        xd##g.x = ok3 ? xd##g.x : 0.f; xd##g.y = ok3 ? xd##g.y : 0.f;         \
        xd##g.z = ok3 ? xd##g.z : 0.f; xd##g.w = ok3 ? xd##g.w : 0.f;         \
        ya##g.x = p0 ? ya##g.x : 0.f; ya##g.y = p0 ? ya##g.y : 0.f;           \
        ya##g.z = p0 ? ya##g.z : 0.f; ya##g.w = p0 ? ya##g.w : 0.f;           \
        yb##g.x = p1 ? yb##g.x : 0.f; yb##g.y = p1 ? yb##g.y : 0.f;           \
        yb##g.z = p1 ? yb##g.z : 0.f; yb##g.w = p1 ? yb##g.w : 0.f;           \
        if (lane == 0) {                                                      \
            if (r > 0) { xa##g.x = 0.f; ya##g.x = 0.f; }                      \
            if (r > 1) { xa##g.y = 0.f; ya##g.y = 0.f; }                      \
            if (r > 2) { xa##g.z = 0.f; ya##g.z = 0.f; }                      \
        }                                                                     \
        acc0.x += xa##g.x + ya##g.x; acc0.y += xa##g.y + ya##g.y;             \
        acc0.z += xa##g.z + ya##g.z; acc0.w += xa##g.w + ya##g.w;             \
        acc1.x += xb##g.x + yb##g.x; acc1.y += xb##g.y + yb##g.y;             \
        acc1.z += xb##g.z + yb##g.z; acc1.w += xb##g.w + yb##g.w;             \
        acc2.x += xc##g.x; acc2.y += xc##g.y;                                 \
        acc2.z += xc##g.z; acc2.w += xc##g.w;                                 \
        acc3.x += xd##g.x; acc3.y += xd##g.y;                                 \
        acc3.z += xd##g.z; acc3.w += xd##g.w;                                 \
    }

#define QUADBODY(P0)                                                          \
    {                                                                         \
        ROWPAIR(0, (P0) + 0)                                                  \
        ROWPAIR(1, (P0) + 1)                                                  \
        ROWPAIR(2, (P0) + 2)                                                  \
        ROWPAIR(3, (P0) + 3)                                                  \
        LOADP(0)                                                              \
        LOADP(1)                                                              \
        LOADP(2)                                                              \
        CONSP(0)                                                              \
        LOADP(3)                                                              \
        CONSP(1)                                                              \
        CONSP(2)                                                              \
        CONSP(3)                                                              \
    }

    QUADBODY(0)
    QUADBODY(4)
#undef ROWPAIR
#undef LOADP
#undef CONSP
#undef QUADBODY
#endif

    // dump: lds[w][4*(lane+64*g)+comp] — bijective onto [0,1024) per wave
    float4* lrow = (float4*)lds[w];
    lrow[lane]       = acc0;
    lrow[lane + 64]  = acc1;
    lrow[lane + 128] = acc2;
    lrow[lane + 192] = acc3;
    if (tid < 64) lds[tid >> 3][1024 + (tid & 7)] = 0.f;   // zero pad tails
    __syncthreads();

    // partial[b][t][d] = sum over 8 waves of lds[wv][d + (wv&3)]; float2 store
    float* outp = partial + ((size_t)b * CHUNKS + t) * NN;
    {
        const int d0 = tid * 2;
        float2 o;
        o.x = ((lds[0][d0]     + lds[1][d0 + 1]) + (lds[2][d0 + 2] + lds[3][d0 + 3]))
            + ((lds[4][d0]     + lds[5][d0 + 1]) + (lds[6][d0 + 2] + lds[7][d0 + 3]));
        o.y = ((lds[0][d0 + 1] + lds[1][d0 + 2]) + (lds[2][d0 + 3] + lds[3][d0 + 4]))
            + ((lds[4][d0 + 1] + lds[5][d0 + 2]) + (lds[6][d0 + 3] + lds[7][d0 + 4]));
        ((float2*)outp)[tid] = o;
    }
}

// ---------------------------------------------------------------------------
// Kernel 2: reduce chunk partials -> parity-split means (CHUNKS=8).
__global__ __launch_bounds__(256) void reduce_waves(const float* __restrict__ partial,
                                                    float* __restrict__ wpm) {
    __shared__ float slo_s[256], shi_s[256];
    const int blk = blockIdx.x;
    const int b = blk >> 3;
    const int dq = blk & 7;
    const int tid = threadIdx.x;
    const int d = dq * 64 + (tid & 63);
    const int cq = tid >> 6;            // 0..3, 2 chunks each
    const float* pb = partial + (size_t)b * CHUNKS * NN;
    float slo = 0.f, shi = 0.f;
#pragma unroll
    for (int j = 0; j < 2; ++j) {
        const int c = cq * 2 + j;
        slo += pb[c * NN + d];
        shi += pb[c * NN + d + 512];
    }
    slo_s[tid] = slo; shi_s[tid] = shi;
    __syncthreads();
    if (tid < 64) {
        const float l = (slo_s[tid] + slo_s[tid + 64]) + (slo_s[tid + 128] + slo_s[tid + 192]);
        const float h = (shi_s[tid] + shi_s[tid + 64]) + (shi_s[tid + 128] + shi_s[tid + 192]);
        const float wlo = l / (float)(NN - d);
        const float whi = h / (float)(512 - d);
        wpm[(size_t)b * NN + d]       = wlo + whi;   // wp
        wpm[(size_t)b * NN + 512 + d] = wlo - whi;   // wm
    }
}

// ---------------------------------------------------------------------------
// Kernel 3: even/odd-decimated DFT, float2 twiddles (R9-exact).
__global__ __launch_bounds__(512) void dft_part(const float* __restrict__ wpm,
                                                float* __restrict__ kparts) {
    __shared__ float wp[512], wm[512];
    __shared__ float2 tw[NN];       // (cos, -sin)
    __shared__ float redmax[8], redsum[8];
    const int ks = blockIdx.x & (KS - 1);
    const int b = blockIdx.x >> 3;
    const int tid = threadIdx.x;
    const float C = 6.283185307179586f / 1024.0f;

    {
        const float* src = wpm + (size_t)b * NN;
        wp[tid & 511] = src[tid & 511];
        wm[tid & 511] = src[512 + (tid & 511)];
        float s0, c0, s1, c1;
        __sincosf((float)tid * C, &s0, &c0);
        __sincosf((float)(tid + 512) * C, &s1, &c1);
        tw[tid]       = make_float2(c0, -s0);
        tw[tid + 512] = make_float2(c1, -s1);
    }
    __syncthreads();

    const int k = 1 + ks * 64 + (tid >> 3);
    const int dp = tid & 7;
    const float* wsel = (k & 1) ? wm : wp;
    const int kstep = (k << 3) & (NN - 1);

    float re = 0.f, im = 0.f;
    int t = (k * dp) & (NN - 1);
#pragma unroll 8
    for (int it = 0; it < 64; ++it) {
        const float2 c = tw[t];
        const float wv = wsel[dp + 8 * it];
        re = fmaf(wv, c.x, re);
        im = fmaf(wv, c.y, im);
        t = (t + kstep) & (NN - 1);
    }
    re += __shfl_xor(re, 1, 64); re += __shfl_xor(re, 2, 64); re += __shfl_xor(re, 4, 64);
    im += __shfl_xor(im, 1, 64); im += __shfl_xor(im, 2, 64); im += __shfl_xor(im, 4, 64);
    const float spec = sqrtf(re * re + im * im);

    float mx = spec;
    float sm = (dp == 0) ? spec : 0.f;
    for (int off = 8; off < 64; off <<= 1) {
        mx = fmaxf(mx, __shfl_xor(mx, off, 64));
        sm += __shfl_xor(sm, off, 64);
    }
    const int wid = tid >> 6, lane = tid & 63;
    if (lane == 0) { redmax[wid] = mx; redsum[wid] = sm; }
    __syncthreads();
    if (tid == 0) {
        float M = redmax[0], S = redsum[0];
        for (int i = 1; i < 8; ++i) { M = fmaxf(M, redmax[i]); S += redsum[i]; }
        kparts[((size_t)b * KS + ks) * 2 + 0] = M;
        kparts[((size_t)b * KS + ks) * 2 + 1] = S;
    }
}

// ---------------------------------------------------------------------------
// Kernel 4: judgement per batch, mean over batches (R9-exact).
__global__ __launch_bounds__(64) void finalize(const float* __restrict__ kparts,
                                               float* __restrict__ out) {
    const int lane = threadIdx.x;
    float M = 0.f, S = 0.f;
#pragma unroll
    for (int s = 0; s < KS; ++s) {
        M = fmaxf(M, kparts[((size_t)lane * KS + s) * 2 + 0]);
        S += kparts[((size_t)lane * KS + s) * 2 + 1];
    }
    float j = 1.0f - M / S;
    for (int off = 32; off; off >>= 1) j += __shfl_xor(j, off, 64);
    if (lane == 0) out[0] = j * (1.0f / 64.0f);
}

// ---------------------------------------------------------------------------
extern "C" void kernel_launch(void* const* d_in, const int* in_sizes, int n_in,
                              void* d_out, int out_size, void* d_ws, size_t ws_size,
                              hipStream_t stream) {
    const float* attns = (const float*)d_in[0];
    float* out = (float*)d_out;

    // workspace: [partial: B*CHUNKS*N = 2MB] [wpm: B*N] [kparts: B*KS*2]
    float* partial = (float*)d_ws;
    float* wpm     = partial + (size_t)BB * CHUNKS * NN;
    float* kparts  = wpm + (size_t)BB * NN;

    diag_partial<<<dim3(CHUNKS, BB), 512, 0, stream>>>(attns, partial);
    reduce_waves<<<BB * 8, 256, 0, stream>>>(partial, wpm);
    dft_part<<<BB * KS, 512, 0, stream>>>(wpm, kparts);
    finalize<<<1, 64, 0, stream>>>(kparts, out);
}

// Round 17
// 38.003 us; speedup vs baseline: 6.2837x; 1.0163x over previous
//
#include <hip/hip_runtime.h>

#define NN 1024
#define BB 64
#define CHUNKS 8
#define KS 8   // k-splits per batch in the DFT kernel

#if __has_builtin(__builtin_amdgcn_make_buffer_rsrc) && __has_builtin(__builtin_amdgcn_raw_buffer_load_b128)
#define USE_SRD 1
#else
#define USE_SRD 0
#endif

#if USE_SRD
typedef unsigned int u32x4 __attribute__((ext_vector_type(4)));
static __device__ __forceinline__ float4 srd_load(__amdgpu_buffer_rsrc_t r, int off) {
    u32x4 v = __builtin_amdgcn_raw_buffer_load_b128(r, off, 0, 0);
    float4 f;
    f.x = __uint_as_float(v.x);
    f.y = __uint_as_float(v.y);
    f.z = __uint_as_float(v.z);
    f.w = __uint_as_float(v.w);
    return f;
}
#endif

// ---------------------------------------------------------------------------
// Kernel 1: balanced diagonal partial sums, v9 (R15-exact: CHUNKS=8, SRD).
__global__ __launch_bounds__(512) void diag_partial(const float* __restrict__ attns,
                                                    float* __restrict__ partial) {
    __shared__ float lds[8][1032];
    const int t = blockIdx.x;       // 0..7
    const int b = blockIdx.y;
    const int tid = threadIdx.x;
    const int w = tid >> 6, lane = tid & 63;
    const int r = w & 3;
    const int whi = w >> 2;

    float4 acc0 = make_float4(0.f, 0.f, 0.f, 0.f);
    float4 acc1 = acc0, acc2 = acc0, acc3 = acc0;

    const float* base = attns + (size_t)b * NN * NN;

#if USE_SRD
    const int voff = lane * 16;

#define ROWPAIR(g, p)                                                         \
    const int jbT##g = 64 * t + 8 * (p) + 4 * whi;                            \
    const int nvT##g = 256 - ((jbT##g) >> 2);                                 \
    __amdgpu_buffer_rsrc_t srdT##g = __builtin_amdgcn_make_buffer_rsrc(       \
        (void*)(base + (size_t)(jbT##g + r) * NN + jbT##g), (short)0,         \
        nvT##g * 16, 0x00020000);                                             \
    const int jbB##g = 960 - 64 * t + 8 * (p) + 4 * whi;                      \
    const int nvB##g = 256 - ((jbB##g) >> 2);                                 \
    __amdgpu_buffer_rsrc_t srdB##g = __builtin_amdgcn_make_buffer_rsrc(       \
        (void*)(base + (size_t)(jbB##g + r) * NN + jbB##g), (short)0,         \
        nvB##g * 16, 0x00020000);

#define LOADP(g)                                                              \
    float4 xa##g = srd_load(srdT##g, voff);                                   \
    float4 xb##g = srd_load(srdT##g, voff + 1024);                            \
    float4 xc##g = srd_load(srdT##g, voff + 2048);                            \
    float4 xd##g = srd_load(srdT##g, voff + 3072);                            \
    float4 ya##g = srd_load(srdB##g, voff);                                   \
    float4 yb##g = srd_load(srdB##g, voff + 1024);

#define CONSP(g)                                                              \
    {                                                                         \
        if (lane == 0) {                                                      \
            if (r > 0) { xa##g.x = 0.f; ya##g.x = 0.f; }                      \
            if (r > 1) { xa##g.y = 0.f; ya##g.y = 0.f; }                      \
            if (r > 2) { xa##g.z = 0.f; ya##g.z = 0.f; }                      \
        }                                                                     \
        acc0.x += xa##g.x + ya##g.x; acc0.y += xa##g.y + ya##g.y;             \
        acc0.z += xa##g.z + ya##g.z; acc0.w += xa##g.w + ya##g.w;             \
        acc1.x += xb##g.x + yb##g.x; acc1.y += xb##g.y + yb##g.y;             \
        acc1.z += xb##g.z + yb##g.z; acc1.w += xb##g.w + yb##g.w;             \
        acc2.x += xc##g.x; acc2.y += xc##g.y;                                 \
        acc2.z += xc##g.z; acc2.w += xc##g.w;                                 \
        acc3.x += xd##g.x; acc3.y += xd##g.y;                                 \
        acc3.z += xd##g.z; acc3.w += xd##g.w;                                 \
    }

#define QUADBODY(P0)                                                          \
    {                                                                         \
        ROWPAIR(0, (P0) + 0)                                                  \
        ROWPAIR(1, (P0) + 1)                                                  \
        ROWPAIR(2, (P0) + 2)                                                  \
        ROWPAIR(3, (P0) + 3)                                                  \
        LOADP(0)                                                              \
        LOADP(1)                                                              \
        LOADP(2)                                                              \
        CONSP(0)                                                              \
        LOADP(3)                                                              \
        CONSP(1)                                                              \
        CONSP(2)                                                              \
        CONSP(3)                                                              \
    }

    QUADBODY(0)
    QUADBODY(4)
#undef ROWPAIR
#undef LOADP
#undef CONSP
#undef QUADBODY

#else  // fallback: clamp+mask path (R9 mechanics, 8-wave geometry)

#define ROWPAIR(g, p)                                                         \
    const int jbT##g = 64 * t + 8 * (p) + 4 * whi;                            \
    const int nvT##g = 256 - ((jbT##g) >> 2);                                 \
    const float4* fT##g = (const float4*)(base + (size_t)(jbT##g + r) * NN + jbT##g); \
    const int jbB##g = 960 - 64 * t + 8 * (p) + 4 * whi;                      \
    const int nvB##g = 256 - ((jbB##g) >> 2);                                 \
    const float4* fB##g = (const float4*)(base + (size_t)(jbB##g + r) * NN + jbB##g);

#define LOADP(g)                                                              \
    float4 xa##g = fT##g[lane];                                               \
    float4 xb##g = fT##g[lane + 64];                                          \
    float4 xc##g = fT##g[lane + 128 < nvT##g - 1 ? lane + 128 : nvT##g - 1];  \
    float4 xd##g = fT##g[lane + 192 < nvT##g - 1 ? lane + 192 : nvT##g - 1];  \
    float4 ya##g = fB##g[lane < nvB##g - 1 ? lane : nvB##g - 1];              \
    float4 yb##g = fB##g[lane + 64 < nvB##g - 1 ? lane + 64 : nvB##g - 1];

#define CONSP(g)                                                              \
    {                                                                         \
        const bool ok2 = lane + 128 < nvT##g, ok3 = lane + 192 < nvT##g;      \
        const bool p0 = lane < nvB##g, p1 = lane + 64 < nvB##g;               \
        xc##g.x = ok2 ? xc##g.x : 0.f; xc##g.y = ok2 ? xc##g.y : 0.f;         \
        xc##g.z = ok2 ? xc##g.z : 0.f; xc##g.w = ok2 ? xc##g.w : 0.f;         \
        xd##g.x = ok3 ? xd##g.x : 0.f; xd##g.y = ok3 ? xd##g.y : 0.f;         \
        xd##g.z = ok3 ? xd##g.z : 0.f; xd##g.w = ok3 ? xd##g.w : 0.f;         \
        ya##g.x = p0 ? ya##g.x : 0.f; ya##g.y = p0 ? ya##g.y : 0.f;           \
        ya##g.z = p0 ? ya##g.z : 0.f; ya##g.w = p0 ? ya##g.w : 0.f;           \
        yb##g.x = p1 ? yb##g.x : 0.f; yb##g.y = p1 ? yb##g.y : 0.f;           \
        yb##g.z = p1 ? yb##g.z : 0.f; yb##g.w = p1 ? yb##g.w : 0.f;           \
        if (lane == 0) {                                                      \
            if (r > 0) { xa##g.x = 0.f; ya##g.x = 0.f; }                      \
            if (r > 1) { xa##g.y = 0.f; ya##g.y = 0.f; }                      \
            if (r > 2) { xa##g.z = 0.f; ya##g.z = 0.f; }                      \
        }                                                                     \
        acc0.x += xa##g.x + ya##g.x; acc0.y += xa##g.y + ya##g.y;             \
        acc0.z += xa##g.z + ya##g.z; acc0.w += xa##g.w + ya##g.w;             \
        acc1.x += xb##g.x + yb##g.x; acc1.y += xb##g.y + yb##g.y;             \
        acc1.z += xb##g.z + yb##g.z; acc1.w += xb##g.w + yb##g.w;             \
        acc2.x += xc##g.x; acc2.y += xc##g.y;                                 \
        acc2.z += xc##g.z; acc2.w += xc##g.w;                                 \
        acc3.x += xd##g.x; acc3.y += xd##g.y;                                 \
        acc3.z += xd##g.z; acc3.w += xd##g.w;                                 \
    }

#define QUADBODY(P0)                                                          \
    {                                                                         \
        ROWPAIR(0, (P0) + 0)                                                  \
        ROWPAIR(1, (P0) + 1)                                                  \
        ROWPAIR(2, (P0) + 2)                                                  \
        ROWPAIR(3, (P0) + 3)                                                  \
        LOADP(0)                                                              \
        LOADP(1)                                                              \
        LOADP(2)                                                              \
        CONSP(0)                                                              \
        LOADP(3)                                                              \
        CONSP(1)                                                              \
        CONSP(2)                                                              \
        CONSP(3)                                                              \
    }

    QUADBODY(0)
    QUADBODY(4)
#undef ROWPAIR
#undef LOADP
#undef CONSP
#undef QUADBODY
#endif

    // dump: lds[w][4*(lane+64*g)+comp] — bijective onto [0,1024) per wave
    float4* lrow = (float4*)lds[w];
    lrow[lane]       = acc0;
    lrow[lane + 64]  = acc1;
    lrow[lane + 128] = acc2;
    lrow[lane + 192] = acc3;
    if (tid < 64) lds[tid >> 3][1024 + (tid & 7)] = 0.f;   // zero pad tails
    __syncthreads();

    // partial[b][t][d] = sum over 8 waves of lds[wv][d + (wv&3)]; float2 store
    float* outp = partial + ((size_t)b * CHUNKS + t) * NN;
    {
        const int d0 = tid * 2;
        float2 o;
        o.x = ((lds[0][d0]     + lds[1][d0 + 1]) + (lds[2][d0 + 2] + lds[3][d0 + 3]))
            + ((lds[4][d0]     + lds[5][d0 + 1]) + (lds[6][d0 + 2] + lds[7][d0 + 3]));
        o.y = ((lds[0][d0 + 1] + lds[1][d0 + 2]) + (lds[2][d0 + 3] + lds[3][d0 + 4]))
            + ((lds[4][d0 + 1] + lds[5][d0 + 2]) + (lds[6][d0 + 3] + lds[7][d0 + 4]));
        ((float2*)outp)[tid] = o;
    }
}

// ---------------------------------------------------------------------------
// Kernel 2: fused reduce + even/odd-decimated DFT. Each block re-reduces its
// batch's 8 chunk-partials (32 KB, L2-hot after first of 8 blocks/batch)
// directly into wp/wm — removes the reduce_waves launch + gap. No ticket.
__global__ __launch_bounds__(512) void dft_part(const float* __restrict__ partial,
                                                float* __restrict__ kparts) {
    __shared__ float wp[512], wm[512];
    __shared__ float2 tw[NN];       // (cos, -sin)
    __shared__ float redmax[8], redsum[8];
    const int ks = blockIdx.x & (KS - 1);
    const int b = blockIdx.x >> 3;
    const int tid = threadIdx.x;
    const float C = 6.283185307179586f / 1024.0f;

    {
        const float* pb = partial + (size_t)b * CHUNKS * NN;
        float slo = 0.f, shi = 0.f;
#pragma unroll
        for (int c = 0; c < CHUNKS; ++c) {
            slo += pb[c * NN + tid];
            shi += pb[c * NN + tid + 512];
        }
        const float wlo = slo / (float)(NN - tid);
        const float whi = shi / (float)(512 - tid);
        wp[tid] = wlo + whi;
        wm[tid] = wlo - whi;
        float s0, c0, s1, c1;
        __sincosf((float)tid * C, &s0, &c0);
        __sincosf((float)(tid + 512) * C, &s1, &c1);
        tw[tid]       = make_float2(c0, -s0);
        tw[tid + 512] = make_float2(c1, -s1);
    }
    __syncthreads();

    const int k = 1 + ks * 64 + (tid >> 3);
    const int dp = tid & 7;
    const float* wsel = (k & 1) ? wm : wp;
    const int kstep = (k << 3) & (NN - 1);

    float re = 0.f, im = 0.f;
    int t = (k * dp) & (NN - 1);
#pragma unroll 8
    for (int it = 0; it < 64; ++it) {
        const float2 c = tw[t];
        const float wv = wsel[dp + 8 * it];
        re = fmaf(wv, c.x, re);
        im = fmaf(wv, c.y, im);
        t = (t + kstep) & (NN - 1);
    }
    re += __shfl_xor(re, 1, 64); re += __shfl_xor(re, 2, 64); re += __shfl_xor(re, 4, 64);
    im += __shfl_xor(im, 1, 64); im += __shfl_xor(im, 2, 64); im += __shfl_xor(im, 4, 64);
    const float spec = sqrtf(re * re + im * im);

    float mx = spec;
    float sm = (dp == 0) ? spec : 0.f;
    for (int off = 8; off < 64; off <<= 1) {
        mx = fmaxf(mx, __shfl_xor(mx, off, 64));
        sm += __shfl_xor(sm, off, 64);
    }
    const int wid = tid >> 6, lane = tid & 63;
    if (lane == 0) { redmax[wid] = mx; redsum[wid] = sm; }
    __syncthreads();
    if (tid == 0) {
        float M = redmax[0], S = redsum[0];
        for (int i = 1; i < 8; ++i) { M = fmaxf(M, redmax[i]); S += redsum[i]; }
        kparts[((size_t)b * KS + ks) * 2 + 0] = M;
        kparts[((size_t)b * KS + ks) * 2 + 1] = S;
    }
}

// ---------------------------------------------------------------------------
// Kernel 3: judgement per batch, mean over batches.
__global__ __launch_bounds__(64) void finalize(const float* __restrict__ kparts,
                                               float* __restrict__ out) {
    const int lane = threadIdx.x;
    float M = 0.f, S = 0.f;
#pragma unroll
    for (int s = 0; s < KS; ++s) {
        M = fmaxf(M, kparts[((size_t)lane * KS + s) * 2 + 0]);
        S += kparts[((size_t)lane * KS + s) * 2 + 1];
    }
    float j = 1.0f - M / S;
    for (int off = 32; off; off >>= 1) j += __shfl_xor(j, off, 64);
    if (lane == 0) out[0] = j * (1.0f / 64.0f);
}

// ---------------------------------------------------------------------------
extern "C" void kernel_launch(void* const* d_in, const int* in_sizes, int n_in,
                              void* d_out, int out_size, void* d_ws, size_t ws_size,
                              hipStream_t stream) {
    const float* attns = (const float*)d_in[0];
    float* out = (float*)d_out;

    // workspace: [partial: B*CHUNKS*N = 2MB] [kparts: B*KS*2]
    float* partial = (float*)d_ws;
    float* kparts  = partial + (size_t)BB * CHUNKS * NN;

    diag_partial<<<dim3(CHUNKS, BB), 512, 0, stream>>>(attns, partial);
    dft_part<<<BB * KS, 512, 0, stream>>>(partial, kparts);
    finalize<<<1, 64, 0, stream>>>(kparts, out);
}